// Round 1
// baseline (1000.965 us; speedup 1.0000x reference)
//
#include <hip/hip_runtime.h>
#include <hip/hip_bf16.h>

#define T_TOK 8192
#define D_DIM 1024
#define F_DIM 4096
#define E_NUM 8
#define BM 128
#define MAX_ROWS (2 * T_TOK + E_NUM * BM)   // 17408
#define NUM_RB (MAX_ROWS / BM)              // 136

typedef __hip_bfloat16 bf16;
using bf16x8  = __attribute__((ext_vector_type(8))) __bf16;
using u16x8   = __attribute__((ext_vector_type(8))) unsigned short;
using float4v = __attribute__((ext_vector_type(4))) float;

__device__ inline u16x8 zu8() {
    u16x8 v;
#pragma unroll
    for (int i = 0; i < 8; ++i) v[i] = 0;
    return v;
}

// ---------------- x -> bf16 ----------------
__global__ __launch_bounds__(256) void xcvt_kernel(const float* __restrict__ x,
                                                   bf16* __restrict__ xb) {
    const int i = blockIdx.x * 256 + threadIdx.x;  // over T*D/4
    float4 v = ((const float4*)x)[i];
    bf16 tmp[4];
    tmp[0] = __float2bfloat16(v.x);
    tmp[1] = __float2bfloat16(v.y);
    tmp[2] = __float2bfloat16(v.z);
    tmp[3] = __float2bfloat16(v.w);
    ((ushort4*)xb)[i] = *(const ushort4*)tmp;
}

// ---------------- transpose+convert: src[e][M][N] f32 -> dst[e][N][M] bf16 ----
__global__ __launch_bounds__(256) void transpose_cvt(const float* __restrict__ src,
                                                     bf16* __restrict__ dst,
                                                     int M, int N) {
    __shared__ float tile[32][33];
    const int e = blockIdx.z;
    const float* s = src + (size_t)e * M * N;
    bf16* d = dst + (size_t)e * M * N;
    const int n0 = blockIdx.x * 32, m0 = blockIdx.y * 32;
#pragma unroll
    for (int i = 0; i < 4; ++i) {
        int m = m0 + threadIdx.y + i * 8;
        tile[threadIdx.y + i * 8][threadIdx.x] = s[(size_t)m * N + n0 + threadIdx.x];
    }
    __syncthreads();
#pragma unroll
    for (int i = 0; i < 4; ++i) {
        int n = n0 + threadIdx.y + i * 8;
        d[(size_t)n * M + m0 + threadIdx.x] =
            __float2bfloat16(tile[threadIdx.x][threadIdx.y + i * 8]);
    }
}

// ---------------- router: logits (fp32), top-2, softmax, counts ----------------
__global__ __launch_bounds__(256) void router_kernel(
    const float* __restrict__ x, const float* __restrict__ Wg,
    const float* __restrict__ bg, int* __restrict__ top_idx,
    float* __restrict__ top_gate, int* __restrict__ counts) {
    __shared__ float wg_s[E_NUM][D_DIM];
    for (int i = threadIdx.x; i < D_DIM * E_NUM; i += 256)
        wg_s[i & 7][i >> 3] = Wg[i];
    __syncthreads();

    const int lane = threadIdx.x & 63;
    const int t = blockIdx.x * 4 + (threadIdx.x >> 6);
    float acc[E_NUM];
#pragma unroll
    for (int e = 0; e < E_NUM; ++e) acc[e] = 0.f;
    const float* xrow = x + (size_t)t * D_DIM;
    for (int d = lane; d < D_DIM; d += 64) {
        const float xv = xrow[d];
#pragma unroll
        for (int e = 0; e < E_NUM; ++e) acc[e] += xv * wg_s[e][d];
    }
#pragma unroll
    for (int off = 32; off > 0; off >>= 1) {
#pragma unroll
        for (int e = 0; e < E_NUM; ++e) acc[e] += __shfl_xor(acc[e], off, 64);
    }
    if (lane == 0) {
        float v[E_NUM];
#pragma unroll
        for (int e = 0; e < E_NUM; ++e) v[e] = acc[e] + bg[e];
        int i0 = 0;
#pragma unroll
        for (int e = 1; e < E_NUM; ++e)
            if (v[e] > v[i0]) i0 = e;
        int i1 = -1;
#pragma unroll
        for (int e = 0; e < E_NUM; ++e) {
            if (e == i0) continue;
            if (i1 < 0 || v[e] > v[i1]) i1 = e;
        }
        const float g0 = 1.f / (1.f + expf(v[i1] - v[i0]));
        top_idx[2 * t] = i0;
        top_idx[2 * t + 1] = i1;
        top_gate[2 * t] = g0;
        top_gate[2 * t + 1] = 1.f - g0;
        atomicAdd(&counts[i0], 1);
        atomicAdd(&counts[i1], 1);
    }
}

// ---------------- padded segment offsets ----------------
__global__ void offsets_kernel(const int* __restrict__ counts, int* __restrict__ offsets) {
    if (threadIdx.x == 0) {
        int off = 0;
#pragma unroll
        for (int e = 0; e < E_NUM; ++e) {
            offsets[e] = off;
            off += (counts[e] + BM - 1) / BM * BM;
        }
        offsets[E_NUM] = off;
    }
}

// ---------------- scatter tokens into expert segments ----------------
__global__ __launch_bounds__(256) void scatter_kernel(
    const int* __restrict__ top_idx, const float* __restrict__ top_gate,
    const int* __restrict__ offsets, int* __restrict__ cursors,
    int* __restrict__ tok_list, float* __restrict__ gate_list) {
    const int t = blockIdx.x * 256 + threadIdx.x;
    if (t >= T_TOK) return;
#pragma unroll
    for (int j = 0; j < 2; ++j) {
        const int e = top_idx[2 * t + j];
        const int pos = atomicAdd(&cursors[e], 1);
        const int slot = offsets[e] + pos;
        tok_list[slot] = t;
        gate_list[slot] = top_gate[2 * t + j];
    }
}

// ---------------- GEMM1: h = relu(gather(x) @ W1[e] + b1[e]) -> bf16 ----------
__global__ __launch_bounds__(256, 2) void gemm1_kernel(
    const bf16* __restrict__ xb, const bf16* __restrict__ W1t,
    const float* __restrict__ b1, const int* __restrict__ tok_list,
    const int* __restrict__ offsets, bf16* __restrict__ hbuf) {
    __shared__ bf16 As[BM][40];
    __shared__ bf16 Bs[BM][40];
    __shared__ int toks[BM];

    const int row0 = blockIdx.x * BM;
    const int total = offsets[E_NUM];
    if (row0 >= total) return;
    int e = 0;
#pragma unroll
    for (int i = 1; i < E_NUM; ++i) e += (row0 >= offsets[i]) ? 1 : 0;

    const int tid = threadIdx.x;
    const int f0 = blockIdx.y * 128;

    if (tid < BM) toks[tid] = tok_list[row0 + tid];
    __syncthreads();

    const int srow = tid >> 1, shalf = tid & 1;
    const int tA = toks[srow];
    const bool aValid = (tA >= 0);
    const bf16* aRow = xb + (aValid ? (size_t)tA * D_DIM : 0) + shalf * 16;
    const bf16* bRow = W1t + ((size_t)e * F_DIM + (f0 + srow)) * D_DIM + shalf * 16;
    bf16* aDst = &As[srow][shalf * 16];
    bf16* bDst = &Bs[srow][shalf * 16];

    const int lane = tid & 63;
    const int wv = tid >> 6;
    const int wrow = (wv >> 1) * 64, wcol = (wv & 1) * 64;
    const int fr = lane & 15, fk = (lane >> 4) * 8;

    float4v acc[4][4];
#pragma unroll
    for (int m = 0; m < 4; ++m)
#pragma unroll
        for (int n = 0; n < 4; ++n)
#pragma unroll
            for (int r = 0; r < 4; ++r) acc[m][n][r] = 0.f;

    const int NKT = D_DIM / 32;
    u16x8 ra0 = zu8(), ra1 = zu8(), rb0, rb1;
    if (aValid) {
        ra0 = *(const u16x8*)(aRow);
        ra1 = *(const u16x8*)(aRow + 8);
    }
    rb0 = *(const u16x8*)(bRow);
    rb1 = *(const u16x8*)(bRow + 8);

    for (int kt = 0; kt < NKT; ++kt) {
        __syncthreads();
        *(u16x8*)aDst = ra0;
        *(u16x8*)(aDst + 8) = ra1;
        *(u16x8*)bDst = rb0;
        *(u16x8*)(bDst + 8) = rb1;
        __syncthreads();
        if (kt + 1 < NKT) {
            const int ko = (kt + 1) * 32;
            if (aValid) {
                ra0 = *(const u16x8*)(aRow + ko);
                ra1 = *(const u16x8*)(aRow + ko + 8);
            }
            rb0 = *(const u16x8*)(bRow + ko);
            rb1 = *(const u16x8*)(bRow + ko + 8);
        }
        bf16x8 af[4], bfr[4];
#pragma unroll
        for (int m = 0; m < 4; ++m) af[m] = *(const bf16x8*)&As[wrow + m * 16 + fr][fk];
#pragma unroll
        for (int n = 0; n < 4; ++n) bfr[n] = *(const bf16x8*)&Bs[wcol + n * 16 + fr][fk];
#pragma unroll
        for (int m = 0; m < 4; ++m)
#pragma unroll
            for (int n = 0; n < 4; ++n)
                acc[m][n] = __builtin_amdgcn_mfma_f32_16x16x32_bf16(af[m], bfr[n],
                                                                   acc[m][n], 0, 0, 0);
    }

#pragma unroll
    for (int n = 0; n < 4; ++n) {
        const int gcol = f0 + wcol + n * 16 + fr;
        const float bias = b1[e * F_DIM + gcol];
#pragma unroll
        for (int m = 0; m < 4; ++m) {
#pragma unroll
            for (int r = 0; r < 4; ++r) {
                const int grow = row0 + wrow + m * 16 + (lane >> 4) * 4 + r;
                float v = acc[m][n][r] + bias;
                v = fmaxf(v, 0.f);
                hbuf[(size_t)grow * F_DIM + gcol] = __float2bfloat16(v);
            }
        }
    }
}

// ---------------- GEMM2: out[tok] += gate * (h @ W2[e] + b2[e]) ----------------
__global__ __launch_bounds__(256, 2) void gemm2_kernel(
    const bf16* __restrict__ hbuf, const bf16* __restrict__ W2t,
    const float* __restrict__ b2, const int* __restrict__ tok_list,
    const float* __restrict__ gate_list, const int* __restrict__ offsets,
    float* __restrict__ out) {
    __shared__ bf16 As[BM][40];
    __shared__ bf16 Bs[BM][40];
    __shared__ int toks[BM];
    __shared__ float gates_s[BM];

    const int row0 = blockIdx.x * BM;
    const int total = offsets[E_NUM];
    if (row0 >= total) return;
    int e = 0;
#pragma unroll
    for (int i = 1; i < E_NUM; ++i) e += (row0 >= offsets[i]) ? 1 : 0;

    const int tid = threadIdx.x;
    const int d0 = blockIdx.y * 128;

    if (tid < BM) {
        int t = tok_list[row0 + tid];
        toks[tid] = t;
        gates_s[tid] = (t >= 0) ? gate_list[row0 + tid] : 0.f;
    }
    __syncthreads();

    const int srow = tid >> 1, shalf = tid & 1;
    const bf16* aRow = hbuf + (size_t)(row0 + srow) * F_DIM + shalf * 16;
    const bf16* bRow = W2t + ((size_t)e * D_DIM + (d0 + srow)) * F_DIM + shalf * 16;
    bf16* aDst = &As[srow][shalf * 16];
    bf16* bDst = &Bs[srow][shalf * 16];

    const int lane = tid & 63;
    const int wv = tid >> 6;
    const int wrow = (wv >> 1) * 64, wcol = (wv & 1) * 64;
    const int fr = lane & 15, fk = (lane >> 4) * 8;

    float4v acc[4][4];
#pragma unroll
    for (int m = 0; m < 4; ++m)
#pragma unroll
        for (int n = 0; n < 4; ++n)
#pragma unroll
            for (int r = 0; r < 4; ++r) acc[m][n][r] = 0.f;

    const int NKT = F_DIM / 32;
    u16x8 ra0 = *(const u16x8*)(aRow);
    u16x8 ra1 = *(const u16x8*)(aRow + 8);
    u16x8 rb0 = *(const u16x8*)(bRow);
    u16x8 rb1 = *(const u16x8*)(bRow + 8);

    for (int kt = 0; kt < NKT; ++kt) {
        __syncthreads();
        *(u16x8*)aDst = ra0;
        *(u16x8*)(aDst + 8) = ra1;
        *(u16x8*)bDst = rb0;
        *(u16x8*)(bDst + 8) = rb1;
        __syncthreads();
        if (kt + 1 < NKT) {
            const int ko = (kt + 1) * 32;
            ra0 = *(const u16x8*)(aRow + ko);
            ra1 = *(const u16x8*)(aRow + ko + 8);
            rb0 = *(const u16x8*)(bRow + ko);
            rb1 = *(const u16x8*)(bRow + ko + 8);
        }
        bf16x8 af[4], bfr[4];
#pragma unroll
        for (int m = 0; m < 4; ++m) af[m] = *(const bf16x8*)&As[wrow + m * 16 + fr][fk];
#pragma unroll
        for (int n = 0; n < 4; ++n) bfr[n] = *(const bf16x8*)&Bs[wcol + n * 16 + fr][fk];
#pragma unroll
        for (int m = 0; m < 4; ++m)
#pragma unroll
            for (int n = 0; n < 4; ++n)
                acc[m][n] = __builtin_amdgcn_mfma_f32_16x16x32_bf16(af[m], bfr[n],
                                                                   acc[m][n], 0, 0, 0);
    }

#pragma unroll
    for (int n = 0; n < 4; ++n) {
        const int gcol = d0 + wcol + n * 16 + fr;
        const float bias = b2[e * D_DIM + gcol];
#pragma unroll
        for (int m = 0; m < 4; ++m) {
#pragma unroll
            for (int r = 0; r < 4; ++r) {
                const int lrow = wrow + m * 16 + (lane >> 4) * 4 + r;
                const int t = toks[lrow];
                if (t >= 0) {
                    const float v = (acc[m][n][r] + bias) * gates_s[lrow];
                    atomicAdd(&out[(size_t)t * D_DIM + gcol], v);
                }
            }
        }
    }
}

extern "C" void kernel_launch(void* const* d_in, const int* in_sizes, int n_in,
                              void* d_out, int out_size, void* d_ws, size_t ws_size,
                              hipStream_t stream) {
    const float* x = (const float*)d_in[0];
    const float* Wg = (const float*)d_in[1];
    const float* bg = (const float*)d_in[2];
    const float* W1 = (const float*)d_in[3];
    const float* b1 = (const float*)d_in[4];
    const float* W2 = (const float*)d_in[5];
    const float* b2 = (const float*)d_in[6];
    float* out = (float*)d_out;

    char* ws = (char*)d_ws;
    int* counts = (int*)(ws + 0);       // 8 ints
    int* cursors = (int*)(ws + 32);     // 8 ints
    int* offsets = (int*)(ws + 64);     // 9 ints
    int* top_idx = (int*)(ws + 256);                     // T*2 ints
    float* top_gate = (float*)(ws + 256 + 65536);        // T*2 floats
    int* tok_list = (int*)(ws + 256 + 2 * 65536);        // MAX_ROWS ints
    float* gate_list = (float*)(ws + 256 + 2 * 65536 + 69632);
    size_t off = 256 + 2 * 65536 + 2 * 69632;            // 270592, 256-aligned
    bf16* xb = (bf16*)(ws + off);
    off += (size_t)T_TOK * D_DIM * 2;
    bf16* W1t = (bf16*)(ws + off);
    off += (size_t)E_NUM * D_DIM * F_DIM * 2;
    bf16* W2t = (bf16*)(ws + off);
    off += (size_t)E_NUM * D_DIM * F_DIM * 2;
    bf16* hbuf = (bf16*)(ws + off);

    hipMemsetAsync(d_out, 0, (size_t)T_TOK * D_DIM * sizeof(float), stream);
    hipMemsetAsync(ws, 0, 64, stream);                       // counts + cursors
    hipMemsetAsync(tok_list, 0xFF, (size_t)MAX_ROWS * 4, stream);  // -1 sentinels

    xcvt_kernel<<<T_TOK * D_DIM / 4 / 256, 256, 0, stream>>>(x, xb);
    transpose_cvt<<<dim3(F_DIM / 32, D_DIM / 32, E_NUM), dim3(32, 8), 0, stream>>>(
        W1, W1t, D_DIM, F_DIM);
    transpose_cvt<<<dim3(D_DIM / 32, F_DIM / 32, E_NUM), dim3(32, 8), 0, stream>>>(
        W2, W2t, F_DIM, D_DIM);
    router_kernel<<<T_TOK / 4, 256, 0, stream>>>(x, Wg, bg, top_idx, top_gate, counts);
    offsets_kernel<<<1, 64, 0, stream>>>(counts, offsets);
    scatter_kernel<<<T_TOK / 256, 256, 0, stream>>>(top_idx, top_gate, offsets, cursors,
                                                    tok_list, gate_list);
    gemm1_kernel<<<dim3(NUM_RB, F_DIM / 128), 256, 0, stream>>>(xb, W1t, b1, tok_list,
                                                                offsets, hbuf);
    gemm2_kernel<<<dim3(NUM_RB, D_DIM / 128), 256, 0, stream>>>(hbuf, W2t, b2, tok_list,
                                                                gate_list, offsets, out);
}

// Round 2
// 868.967 us; speedup vs baseline: 1.1519x; 1.1519x over previous
//
#include <hip/hip_runtime.h>
#include <hip/hip_bf16.h>

#define T_TOK 8192
#define D_DIM 1024
#define F_DIM 4096
#define E_NUM 8
#define BM 128
#define MAX_ROWS (2 * T_TOK + E_NUM * BM)   // 17408
#define NUM_RB (MAX_ROWS / BM)              // 136

typedef __hip_bfloat16 bf16;
using bf16x8  = __attribute__((ext_vector_type(8))) __bf16;
using float4v = __attribute__((ext_vector_type(4))) float;

// async global->LDS, 16B per lane; dest = uniform base + lane*16
__device__ inline void gl_lds16(const bf16* g, bf16* l) {
    __builtin_amdgcn_global_load_lds(
        (const __attribute__((address_space(1))) void*)g,
        (__attribute__((address_space(3))) void*)l, 16, 0, 0);
}

// ---------------- x -> bf16 ----------------
__global__ __launch_bounds__(256) void xcvt_kernel(const float* __restrict__ x,
                                                   bf16* __restrict__ xb) {
    const int i = blockIdx.x * 256 + threadIdx.x;  // over T*D/4
    float4 v = ((const float4*)x)[i];
    bf16 tmp[4];
    tmp[0] = __float2bfloat16(v.x);
    tmp[1] = __float2bfloat16(v.y);
    tmp[2] = __float2bfloat16(v.z);
    tmp[3] = __float2bfloat16(v.w);
    ((ushort4*)xb)[i] = *(const ushort4*)tmp;
}

// ------- transpose+convert: src[e][M][N] f32 -> dst[e][N][M] bf16, 64x64 tiles -------
__global__ __launch_bounds__(256) void transpose_cvt(const float* __restrict__ src,
                                                     bf16* __restrict__ dst,
                                                     int M, int N) {
    __shared__ float tile[64][65];
    const int e = blockIdx.z;
    const float* s = src + (size_t)e * M * N;
    bf16* d = dst + (size_t)e * M * N;
    const int n0 = blockIdx.x * 64, m0 = blockIdx.y * 64;
    const int tx = threadIdx.x & 15, ty = threadIdx.x >> 4;
#pragma unroll
    for (int i = 0; i < 4; ++i) {
        const int r = ty + i * 16;
        const float4 v = *(const float4*)&s[(size_t)(m0 + r) * N + n0 + tx * 4];
        tile[r][tx * 4 + 0] = v.x;
        tile[r][tx * 4 + 1] = v.y;
        tile[r][tx * 4 + 2] = v.z;
        tile[r][tx * 4 + 3] = v.w;
    }
    __syncthreads();
#pragma unroll
    for (int i = 0; i < 4; ++i) {
        const int nc = ty + i * 16;
        bf16 o[4];
#pragma unroll
        for (int j = 0; j < 4; ++j) o[j] = __float2bfloat16(tile[tx * 4 + j][nc]);
        *(ushort4*)&d[(size_t)(n0 + nc) * M + m0 + tx * 4] = *(const ushort4*)o;
    }
}

// ---------------- router: logits (fp32), top-2, softmax, counts ----------------
__global__ __launch_bounds__(256) void router_kernel(
    const float* __restrict__ x, const float* __restrict__ Wg,
    const float* __restrict__ bg, int* __restrict__ top_idx,
    float* __restrict__ top_gate, int* __restrict__ counts) {
    __shared__ float wg_s[E_NUM][D_DIM];
    for (int i = threadIdx.x; i < D_DIM * E_NUM; i += 256)
        wg_s[i & 7][i >> 3] = Wg[i];
    __syncthreads();

    const int lane = threadIdx.x & 63;
    const int t = blockIdx.x * 4 + (threadIdx.x >> 6);
    float acc[E_NUM];
#pragma unroll
    for (int e = 0; e < E_NUM; ++e) acc[e] = 0.f;
    const float* xrow = x + (size_t)t * D_DIM;
    for (int d = lane; d < D_DIM; d += 64) {
        const float xv = xrow[d];
#pragma unroll
        for (int e = 0; e < E_NUM; ++e) acc[e] += xv * wg_s[e][d];
    }
#pragma unroll
    for (int off = 32; off > 0; off >>= 1) {
#pragma unroll
        for (int e = 0; e < E_NUM; ++e) acc[e] += __shfl_xor(acc[e], off, 64);
    }
    if (lane == 0) {
        float v[E_NUM];
#pragma unroll
        for (int e = 0; e < E_NUM; ++e) v[e] = acc[e] + bg[e];
        int i0 = 0;
#pragma unroll
        for (int e = 1; e < E_NUM; ++e)
            if (v[e] > v[i0]) i0 = e;
        int i1 = -1;
#pragma unroll
        for (int e = 0; e < E_NUM; ++e) {
            if (e == i0) continue;
            if (i1 < 0 || v[e] > v[i1]) i1 = e;
        }
        const float g0 = 1.f / (1.f + expf(v[i1] - v[i0]));
        top_idx[2 * t] = i0;
        top_idx[2 * t + 1] = i1;
        top_gate[2 * t] = g0;
        top_gate[2 * t + 1] = 1.f - g0;
        atomicAdd(&counts[i0], 1);
        atomicAdd(&counts[i1], 1);
    }
}

// ---------------- padded segment offsets ----------------
__global__ void offsets_kernel(const int* __restrict__ counts, int* __restrict__ offsets) {
    if (threadIdx.x == 0) {
        int off = 0;
#pragma unroll
        for (int e = 0; e < E_NUM; ++e) {
            offsets[e] = off;
            off += (counts[e] + BM - 1) / BM * BM;
        }
        offsets[E_NUM] = off;
    }
}

// ---------------- scatter tokens into expert segments ----------------
__global__ __launch_bounds__(256) void scatter_kernel(
    const int* __restrict__ top_idx, const float* __restrict__ top_gate,
    const int* __restrict__ offsets, int* __restrict__ cursors,
    int* __restrict__ tok_list, float* __restrict__ gate_list) {
    const int t = blockIdx.x * 256 + threadIdx.x;
    if (t >= T_TOK) return;
#pragma unroll
    for (int j = 0; j < 2; ++j) {
        const int e = top_idx[2 * t + j];
        const int pos = atomicAdd(&cursors[e], 1);
        const int slot = offsets[e] + pos;
        tok_list[slot] = t;
        gate_list[slot] = top_gate[2 * t + j];
    }
}

// ---------------- GEMM1: h = relu(gather(x) @ W1[e]^T-layout + b1[e]) -> bf16 ----
// m97 structure: global_load_lds width-16 staging, linear LDS [128][32], 2 barriers/K.
__global__ __launch_bounds__(256, 4) void gemm1_kernel(
    const bf16* __restrict__ xb, const bf16* __restrict__ W1t,
    const float* __restrict__ b1, const int* __restrict__ tok_list,
    const int* __restrict__ offsets, bf16* __restrict__ hbuf) {
    __shared__ bf16 As[BM * 32];
    __shared__ bf16 Bs[BM * 32];
    __shared__ int toks[BM];

    // XCD-aware swizzle (nwg = 136*32 = 4352, %8==0): row-block-major chunks
    const int NCB = F_DIM / 128;          // 32
    const int per = (NUM_RB * NCB) / 8;   // 544
    const int flat = blockIdx.x;
    const int sw = (flat & 7) * per + (flat >> 3);
    const int rb = sw / NCB, cb = sw % NCB;

    const int row0 = rb * BM;
    const int total = offsets[E_NUM];
    if (row0 >= total) return;
    int e = 0;
#pragma unroll
    for (int i = 1; i < E_NUM; ++i) e += (row0 >= offsets[i]) ? 1 : 0;

    const int tid = threadIdx.x;
    if (tid < BM) toks[tid] = tok_list[row0 + tid];
    __syncthreads();

    const int lane = tid & 63;
    const int w = tid >> 6;
    const int f0 = cb * 128;

    // staging: chunk = i*256 + w*64 + lane; row = chunk>>2, 16B-col = chunk&3
    const int r0 = w * 16 + (lane >> 2);
    const int r1 = 64 + w * 16 + (lane >> 2);
    const int c16 = lane & 3;
    int t0 = toks[r0]; if (t0 < 0) t0 = 0;
    int t1 = toks[r1]; if (t1 < 0) t1 = 0;
    const bf16* aP0 = xb + (size_t)t0 * D_DIM + c16 * 8;
    const bf16* aP1 = xb + (size_t)t1 * D_DIM + c16 * 8;
    const bf16* bP0 = W1t + ((size_t)e * F_DIM + f0 + r0) * D_DIM + c16 * 8;
    const bf16* bP1 = W1t + ((size_t)e * F_DIM + f0 + r1) * D_DIM + c16 * 8;

    const unsigned dOff0 = __builtin_amdgcn_readfirstlane(w * 1024);
    const unsigned dOff1 = __builtin_amdgcn_readfirstlane(4096 + w * 1024);
    bf16* aD0 = (bf16*)((char*)As + dOff0);
    bf16* aD1 = (bf16*)((char*)As + dOff1);
    bf16* bD0 = (bf16*)((char*)Bs + dOff0);
    bf16* bD1 = (bf16*)((char*)Bs + dOff1);

    const int wrow = (w >> 1) * 64, wcol = (w & 1) * 64;
    const int fr = lane & 15, fk = (lane >> 4) * 8;

    float4v acc[4][4];
#pragma unroll
    for (int m = 0; m < 4; ++m)
#pragma unroll
        for (int n = 0; n < 4; ++n)
#pragma unroll
            for (int r = 0; r < 4; ++r) acc[m][n][r] = 0.f;

    for (int kt = 0; kt < D_DIM / 32; ++kt) {
        gl_lds16(aP0, aD0);
        gl_lds16(aP1, aD1);
        gl_lds16(bP0, bD0);
        gl_lds16(bP1, bD1);
        aP0 += 32; aP1 += 32; bP0 += 32; bP1 += 32;
        __syncthreads();   // vmcnt(0) drain + barrier: tile ready
        bf16x8 af[4], bfr[4];
#pragma unroll
        for (int m = 0; m < 4; ++m)
            af[m] = *(const bf16x8*)&As[(wrow + m * 16 + fr) * 32 + fk];
#pragma unroll
        for (int n = 0; n < 4; ++n)
            bfr[n] = *(const bf16x8*)&Bs[(wcol + n * 16 + fr) * 32 + fk];
#pragma unroll
        for (int m = 0; m < 4; ++m)
#pragma unroll
            for (int n = 0; n < 4; ++n)
                acc[m][n] = __builtin_amdgcn_mfma_f32_16x16x32_bf16(af[m], bfr[n],
                                                                   acc[m][n], 0, 0, 0);
        __syncthreads();   // all waves done reading before next overwrite
    }

#pragma unroll
    for (int n = 0; n < 4; ++n) {
        const int gcol = f0 + wcol + n * 16 + fr;
        const float bias = b1[e * F_DIM + gcol];
#pragma unroll
        for (int m = 0; m < 4; ++m) {
#pragma unroll
            for (int r = 0; r < 4; ++r) {
                const int grow = row0 + wrow + m * 16 + (lane >> 4) * 4 + r;
                float v = acc[m][n][r] + bias;
                v = fmaxf(v, 0.f);
                hbuf[(size_t)grow * F_DIM + gcol] = __float2bfloat16(v);
            }
        }
    }
}

// ---------------- GEMM2: out[tok] += gate * (h @ W2[e] + b2[e]) ----------------
__global__ __launch_bounds__(256, 4) void gemm2_kernel(
    const bf16* __restrict__ hbuf, const bf16* __restrict__ W2t,
    const float* __restrict__ b2, const int* __restrict__ tok_list,
    const float* __restrict__ gate_list, const int* __restrict__ offsets,
    float* __restrict__ out) {
    __shared__ bf16 As[BM * 32];
    __shared__ bf16 Bs[BM * 32];
    __shared__ int toks[BM];
    __shared__ float gates_s[BM];

    // XCD-aware swizzle (nwg = 136*8 = 1088, %8==0)
    const int NCB = D_DIM / 128;          // 8
    const int per = (NUM_RB * NCB) / 8;   // 136
    const int flat = blockIdx.x;
    const int sw = (flat & 7) * per + (flat >> 3);
    const int rb = sw / NCB, cb = sw % NCB;

    const int row0 = rb * BM;
    const int total = offsets[E_NUM];
    if (row0 >= total) return;
    int e = 0;
#pragma unroll
    for (int i = 1; i < E_NUM; ++i) e += (row0 >= offsets[i]) ? 1 : 0;

    const int tid = threadIdx.x;
    if (tid < BM) {
        int t = tok_list[row0 + tid];
        toks[tid] = t;
        gates_s[tid] = (t >= 0) ? gate_list[row0 + tid] : 0.f;
    }
    __syncthreads();

    const int lane = tid & 63;
    const int w = tid >> 6;
    const int d0 = cb * 128;

    const int r0 = w * 16 + (lane >> 2);
    const int r1 = 64 + w * 16 + (lane >> 2);
    const int c16 = lane & 3;
    const bf16* aP0 = hbuf + (size_t)(row0 + r0) * F_DIM + c16 * 8;
    const bf16* aP1 = hbuf + (size_t)(row0 + r1) * F_DIM + c16 * 8;
    const bf16* bP0 = W2t + ((size_t)e * D_DIM + d0 + r0) * F_DIM + c16 * 8;
    const bf16* bP1 = W2t + ((size_t)e * D_DIM + d0 + r1) * F_DIM + c16 * 8;

    const unsigned dOff0 = __builtin_amdgcn_readfirstlane(w * 1024);
    const unsigned dOff1 = __builtin_amdgcn_readfirstlane(4096 + w * 1024);
    bf16* aD0 = (bf16*)((char*)As + dOff0);
    bf16* aD1 = (bf16*)((char*)As + dOff1);
    bf16* bD0 = (bf16*)((char*)Bs + dOff0);
    bf16* bD1 = (bf16*)((char*)Bs + dOff1);

    const int wrow = (w >> 1) * 64, wcol = (w & 1) * 64;
    const int fr = lane & 15, fk = (lane >> 4) * 8;

    float4v acc[4][4];
#pragma unroll
    for (int m = 0; m < 4; ++m)
#pragma unroll
        for (int n = 0; n < 4; ++n)
#pragma unroll
            for (int r = 0; r < 4; ++r) acc[m][n][r] = 0.f;

    for (int kt = 0; kt < F_DIM / 32; ++kt) {
        gl_lds16(aP0, aD0);
        gl_lds16(aP1, aD1);
        gl_lds16(bP0, bD0);
        gl_lds16(bP1, bD1);
        aP0 += 32; aP1 += 32; bP0 += 32; bP1 += 32;
        __syncthreads();
        bf16x8 af[4], bfr[4];
#pragma unroll
        for (int m = 0; m < 4; ++m)
            af[m] = *(const bf16x8*)&As[(wrow + m * 16 + fr) * 32 + fk];
#pragma unroll
        for (int n = 0; n < 4; ++n)
            bfr[n] = *(const bf16x8*)&Bs[(wcol + n * 16 + fr) * 32 + fk];
#pragma unroll
        for (int m = 0; m < 4; ++m)
#pragma unroll
            for (int n = 0; n < 4; ++n)
                acc[m][n] = __builtin_amdgcn_mfma_f32_16x16x32_bf16(af[m], bfr[n],
                                                                   acc[m][n], 0, 0, 0);
        __syncthreads();
    }

#pragma unroll
    for (int n = 0; n < 4; ++n) {
        const int gcol = d0 + wcol + n * 16 + fr;
        const float bias = b2[e * D_DIM + gcol];
#pragma unroll
        for (int m = 0; m < 4; ++m) {
#pragma unroll
            for (int r = 0; r < 4; ++r) {
                const int lrow = wrow + m * 16 + (lane >> 4) * 4 + r;
                const int t = toks[lrow];
                if (t >= 0) {
                    const float v = (acc[m][n][r] + bias) * gates_s[lrow];
                    atomicAdd(&out[(size_t)t * D_DIM + gcol], v);
                }
            }
        }
    }
}

extern "C" void kernel_launch(void* const* d_in, const int* in_sizes, int n_in,
                              void* d_out, int out_size, void* d_ws, size_t ws_size,
                              hipStream_t stream) {
    const float* x = (const float*)d_in[0];
    const float* Wg = (const float*)d_in[1];
    const float* bg = (const float*)d_in[2];
    const float* W1 = (const float*)d_in[3];
    const float* b1 = (const float*)d_in[4];
    const float* W2 = (const float*)d_in[5];
    const float* b2 = (const float*)d_in[6];
    float* out = (float*)d_out;

    char* ws = (char*)d_ws;
    int* counts = (int*)(ws + 0);       // 8 ints
    int* cursors = (int*)(ws + 32);     // 8 ints
    int* offsets = (int*)(ws + 64);     // 9 ints
    int* top_idx = (int*)(ws + 256);                     // T*2 ints
    float* top_gate = (float*)(ws + 256 + 65536);        // T*2 floats
    int* tok_list = (int*)(ws + 256 + 2 * 65536);        // MAX_ROWS ints
    float* gate_list = (float*)(ws + 256 + 2 * 65536 + 69632);
    size_t off = 256 + 2 * 65536 + 2 * 69632;            // 270592, 256-aligned
    bf16* xb = (bf16*)(ws + off);
    off += (size_t)T_TOK * D_DIM * 2;
    bf16* W1t = (bf16*)(ws + off);
    off += (size_t)E_NUM * D_DIM * F_DIM * 2;
    bf16* W2t = (bf16*)(ws + off);
    off += (size_t)E_NUM * D_DIM * F_DIM * 2;
    bf16* hbuf = (bf16*)(ws + off);

    hipMemsetAsync(d_out, 0, (size_t)T_TOK * D_DIM * sizeof(float), stream);
    hipMemsetAsync(ws, 0, 64, stream);                       // counts + cursors
    hipMemsetAsync(tok_list, 0xFF, (size_t)MAX_ROWS * 4, stream);  // -1 sentinels

    xcvt_kernel<<<T_TOK * D_DIM / 4 / 256, 256, 0, stream>>>(x, xb);
    transpose_cvt<<<dim3(F_DIM / 64, D_DIM / 64, E_NUM), dim3(256), 0, stream>>>(
        W1, W1t, D_DIM, F_DIM);
    transpose_cvt<<<dim3(D_DIM / 64, F_DIM / 64, E_NUM), dim3(256), 0, stream>>>(
        W2, W2t, F_DIM, D_DIM);
    router_kernel<<<T_TOK / 4, 256, 0, stream>>>(x, Wg, bg, top_idx, top_gate, counts);
    offsets_kernel<<<1, 64, 0, stream>>>(counts, offsets);
    scatter_kernel<<<T_TOK / 256, 256, 0, stream>>>(top_idx, top_gate, offsets, cursors,
                                                    tok_list, gate_list);
    gemm1_kernel<<<NUM_RB * (F_DIM / 128), 256, 0, stream>>>(xb, W1t, b1, tok_list,
                                                             offsets, hbuf);
    gemm2_kernel<<<NUM_RB * (D_DIM / 128), 256, 0, stream>>>(hbuf, W2t, b2, tok_list,
                                                             gate_list, offsets, out);
}

// Round 3
// 865.641 us; speedup vs baseline: 1.1563x; 1.0038x over previous
//
#include <hip/hip_runtime.h>
#include <hip/hip_bf16.h>

#define T_TOK 8192
#define D_DIM 1024
#define F_DIM 4096
#define E_NUM 8
#define BM 128
#define MAX_ROWS (2 * T_TOK + E_NUM * BM)   // 17408
#define NUM_RB (MAX_ROWS / BM)              // 136

typedef __hip_bfloat16 bf16;
using bf16x8  = __attribute__((ext_vector_type(8))) __bf16;
using float4v = __attribute__((ext_vector_type(4))) float;

// async global->LDS, 16B per lane; dest = uniform base + lane*16
__device__ inline void gl_lds16(const bf16* g, bf16* l) {
    __builtin_amdgcn_global_load_lds(
        (const __attribute__((address_space(1))) void*)g,
        (__attribute__((address_space(3))) void*)l, 16, 0, 0);
}

// ---------------- x -> bf16 ----------------
__global__ __launch_bounds__(256) void xcvt_kernel(const float* __restrict__ x,
                                                   bf16* __restrict__ xb) {
    const int i = blockIdx.x * 256 + threadIdx.x;  // over T*D/4
    float4 v = ((const float4*)x)[i];
    bf16 tmp[4];
    tmp[0] = __float2bfloat16(v.x);
    tmp[1] = __float2bfloat16(v.y);
    tmp[2] = __float2bfloat16(v.z);
    tmp[3] = __float2bfloat16(v.w);
    ((ushort4*)xb)[i] = *(const ushort4*)tmp;
}

// ------- transpose+convert: src[e][M][N] f32 -> dst[e][N][M] bf16, 64x64 tiles -------
__global__ __launch_bounds__(256) void transpose_cvt(const float* __restrict__ src,
                                                     bf16* __restrict__ dst,
                                                     int M, int N) {
    __shared__ float tile[64][65];
    const int e = blockIdx.z;
    const float* s = src + (size_t)e * M * N;
    bf16* d = dst + (size_t)e * M * N;
    const int n0 = blockIdx.x * 64, m0 = blockIdx.y * 64;
    const int tx = threadIdx.x & 15, ty = threadIdx.x >> 4;
#pragma unroll
    for (int i = 0; i < 4; ++i) {
        const int r = ty + i * 16;
        const float4 v = *(const float4*)&s[(size_t)(m0 + r) * N + n0 + tx * 4];
        tile[r][tx * 4 + 0] = v.x;
        tile[r][tx * 4 + 1] = v.y;
        tile[r][tx * 4 + 2] = v.z;
        tile[r][tx * 4 + 3] = v.w;
    }
    __syncthreads();
#pragma unroll
    for (int i = 0; i < 4; ++i) {
        const int nc = ty + i * 16;
        bf16 o[4];
#pragma unroll
        for (int j = 0; j < 4; ++j) o[j] = __float2bfloat16(tile[tx * 4 + j][nc]);
        *(ushort4*)&d[(size_t)(n0 + nc) * M + m0 + tx * 4] = *(const ushort4*)o;
    }
}

// ---------------- router: logits (fp32), top-2, softmax, counts ----------------
__global__ __launch_bounds__(256) void router_kernel(
    const float* __restrict__ x, const float* __restrict__ Wg,
    const float* __restrict__ bg, int* __restrict__ top_idx,
    float* __restrict__ top_gate, int* __restrict__ counts) {
    __shared__ float wg_s[E_NUM][D_DIM];
    for (int i = threadIdx.x; i < D_DIM * E_NUM; i += 256)
        wg_s[i & 7][i >> 3] = Wg[i];
    __syncthreads();

    const int lane = threadIdx.x & 63;
    const int t = blockIdx.x * 4 + (threadIdx.x >> 6);
    float acc[E_NUM];
#pragma unroll
    for (int e = 0; e < E_NUM; ++e) acc[e] = 0.f;
    const float* xrow = x + (size_t)t * D_DIM;
    for (int d = lane; d < D_DIM; d += 64) {
        const float xv = xrow[d];
#pragma unroll
        for (int e = 0; e < E_NUM; ++e) acc[e] += xv * wg_s[e][d];
    }
#pragma unroll
    for (int off = 32; off > 0; off >>= 1) {
#pragma unroll
        for (int e = 0; e < E_NUM; ++e) acc[e] += __shfl_xor(acc[e], off, 64);
    }
    if (lane == 0) {
        float v[E_NUM];
#pragma unroll
        for (int e = 0; e < E_NUM; ++e) v[e] = acc[e] + bg[e];
        int i0 = 0;
#pragma unroll
        for (int e = 1; e < E_NUM; ++e)
            if (v[e] > v[i0]) i0 = e;
        int i1 = -1;
#pragma unroll
        for (int e = 0; e < E_NUM; ++e) {
            if (e == i0) continue;
            if (i1 < 0 || v[e] > v[i1]) i1 = e;
        }
        const float g0 = 1.f / (1.f + expf(v[i1] - v[i0]));
        top_idx[2 * t] = i0;
        top_idx[2 * t + 1] = i1;
        top_gate[2 * t] = g0;
        top_gate[2 * t + 1] = 1.f - g0;
        atomicAdd(&counts[i0], 1);
        atomicAdd(&counts[i1], 1);
    }
}

// ---------------- padded segment offsets ----------------
__global__ void offsets_kernel(const int* __restrict__ counts, int* __restrict__ offsets) {
    if (threadIdx.x == 0) {
        int off = 0;
#pragma unroll
        for (int e = 0; e < E_NUM; ++e) {
            offsets[e] = off;
            off += (counts[e] + BM - 1) / BM * BM;
        }
        offsets[E_NUM] = off;
    }
}

// ---------------- scatter tokens into expert segments ----------------
__global__ __launch_bounds__(256) void scatter_kernel(
    const int* __restrict__ top_idx, const float* __restrict__ top_gate,
    const int* __restrict__ offsets, int* __restrict__ cursors,
    int* __restrict__ tok_list, float* __restrict__ gate_list) {
    const int t = blockIdx.x * 256 + threadIdx.x;
    if (t >= T_TOK) return;
#pragma unroll
    for (int j = 0; j < 2; ++j) {
        const int e = top_idx[2 * t + j];
        const int pos = atomicAdd(&cursors[e], 1);
        const int slot = offsets[e] + pos;
        tok_list[slot] = t;
        gate_list[slot] = top_gate[2 * t + j];
    }
}

// ---------------- GEMM1: h = relu(gather(x) @ W1[e] + b1[e]) -> bf16 ----------
// 2-phase double-buffered m97 structure: stage(next) overlaps compute(cur);
// one vmcnt(0)+barrier (__syncthreads) per K-step. Separate named LDS buffers
// so alias analysis cannot force an early vmcnt before the ds_reads.
__global__ __launch_bounds__(256, 4) void gemm1_kernel(
    const bf16* __restrict__ xb, const bf16* __restrict__ W1t,
    const float* __restrict__ b1, const int* __restrict__ tok_list,
    const int* __restrict__ offsets, bf16* __restrict__ hbuf) {
    __shared__ bf16 As0[BM * 32];
    __shared__ bf16 As1[BM * 32];
    __shared__ bf16 Bs0[BM * 32];
    __shared__ bf16 Bs1[BM * 32];
    __shared__ int toks[BM];

    // XCD-aware swizzle (nwg = 136*32 = 4352, %8==0): row-block-major chunks
    const int NCB = F_DIM / 128;          // 32
    const int per = (NUM_RB * NCB) / 8;   // 544
    const int flat = blockIdx.x;
    const int sw = (flat & 7) * per + (flat >> 3);
    const int rb = sw / NCB, cb = sw % NCB;

    const int row0 = rb * BM;
    const int total = offsets[E_NUM];
    if (row0 >= total) return;
    int e = 0;
#pragma unroll
    for (int i = 1; i < E_NUM; ++i) e += (row0 >= offsets[i]) ? 1 : 0;

    const int tid = threadIdx.x;
    if (tid < BM) toks[tid] = tok_list[row0 + tid];
    __syncthreads();

    const int lane = tid & 63;
    const int w = tid >> 6;
    const int f0 = cb * 128;

    // staging geometry: chunk = i*256 + w*64 + lane; row = chunk>>2, 16B-col = chunk&3
    const int r0 = w * 16 + (lane >> 2);
    const int r1 = 64 + w * 16 + (lane >> 2);
    const int c16 = lane & 3;
    int t0 = toks[r0]; if (t0 < 0) t0 = 0;
    int t1 = toks[r1]; if (t1 < 0) t1 = 0;
    const bf16* aP0 = xb + (size_t)t0 * D_DIM + c16 * 8;
    const bf16* aP1 = xb + (size_t)t1 * D_DIM + c16 * 8;
    const bf16* bP0 = W1t + ((size_t)e * F_DIM + f0 + r0) * D_DIM + c16 * 8;
    const bf16* bP1 = W1t + ((size_t)e * F_DIM + f0 + r1) * D_DIM + c16 * 8;

    const unsigned dO0 = __builtin_amdgcn_readfirstlane(w * 1024);
    const unsigned dO1 = __builtin_amdgcn_readfirstlane(4096 + w * 1024);

    const int wrow = (w >> 1) * 64, wcol = (w & 1) * 64;
    const int fr = lane & 15, fk = (lane >> 4) * 8;

    float4v acc[4][4];
#pragma unroll
    for (int m = 0; m < 4; ++m)
#pragma unroll
        for (int n = 0; n < 4; ++n)
#pragma unroll
            for (int r = 0; r < 4; ++r) acc[m][n][r] = 0.f;

    auto stage = [&](int kt, bf16* A, bf16* B) {
        const int ko = kt * 32;
        gl_lds16(aP0 + ko, (bf16*)((char*)A + dO0));
        gl_lds16(aP1 + ko, (bf16*)((char*)A + dO1));
        gl_lds16(bP0 + ko, (bf16*)((char*)B + dO0));
        gl_lds16(bP1 + ko, (bf16*)((char*)B + dO1));
    };
    auto comp = [&](const bf16* A, const bf16* B) {
        bf16x8 af[4], bfr[4];
#pragma unroll
        for (int m = 0; m < 4; ++m)
            af[m] = *(const bf16x8*)&A[(wrow + m * 16 + fr) * 32 + fk];
#pragma unroll
        for (int n = 0; n < 4; ++n)
            bfr[n] = *(const bf16x8*)&B[(wcol + n * 16 + fr) * 32 + fk];
#pragma unroll
        for (int m = 0; m < 4; ++m)
#pragma unroll
            for (int n = 0; n < 4; ++n)
                acc[m][n] = __builtin_amdgcn_mfma_f32_16x16x32_bf16(af[m], bfr[n],
                                                                   acc[m][n], 0, 0, 0);
    };

    const int NKT = D_DIM / 32;  // 32, even
    stage(0, As0, Bs0);
    __syncthreads();
    for (int kt = 0; kt < NKT; kt += 2) {
        if (kt + 1 < NKT) stage(kt + 1, As1, Bs1);
        comp(As0, Bs0);
        __syncthreads();                       // vmcnt(0)+lgkm+barrier
        if (kt + 2 < NKT) stage(kt + 2, As0, Bs0);
        comp(As1, Bs1);
        __syncthreads();
    }

#pragma unroll
    for (int n = 0; n < 4; ++n) {
        const int gcol = f0 + wcol + n * 16 + fr;
        const float bias = b1[e * F_DIM + gcol];
#pragma unroll
        for (int m = 0; m < 4; ++m) {
#pragma unroll
            for (int r = 0; r < 4; ++r) {
                const int grow = row0 + wrow + m * 16 + (lane >> 4) * 4 + r;
                float v = acc[m][n][r] + bias;
                v = fmaxf(v, 0.f);
                hbuf[(size_t)grow * F_DIM + gcol] = __float2bfloat16(v);
            }
        }
    }
}

// ---------------- GEMM2: out[tok] += gate * (h @ W2[e] + b2[e]) ----------------
__global__ __launch_bounds__(256, 4) void gemm2_kernel(
    const bf16* __restrict__ hbuf, const bf16* __restrict__ W2t,
    const float* __restrict__ b2, const int* __restrict__ tok_list,
    const float* __restrict__ gate_list, const int* __restrict__ offsets,
    float* __restrict__ out) {
    __shared__ bf16 As0[BM * 32];
    __shared__ bf16 As1[BM * 32];
    __shared__ bf16 Bs0[BM * 32];
    __shared__ bf16 Bs1[BM * 32];
    __shared__ int toks[BM];
    __shared__ float gates_s[BM];

    // XCD-aware swizzle (nwg = 136*8 = 1088, %8==0)
    const int NCB = D_DIM / 128;          // 8
    const int per = (NUM_RB * NCB) / 8;   // 136
    const int flat = blockIdx.x;
    const int sw = (flat & 7) * per + (flat >> 3);
    const int rb = sw / NCB, cb = sw % NCB;

    const int row0 = rb * BM;
    const int total = offsets[E_NUM];
    if (row0 >= total) return;
    int e = 0;
#pragma unroll
    for (int i = 1; i < E_NUM; ++i) e += (row0 >= offsets[i]) ? 1 : 0;

    const int tid = threadIdx.x;
    if (tid < BM) {
        int t = tok_list[row0 + tid];
        toks[tid] = t;
        gates_s[tid] = (t >= 0) ? gate_list[row0 + tid] : 0.f;
    }
    __syncthreads();

    const int lane = tid & 63;
    const int w = tid >> 6;
    const int d0 = cb * 128;

    const int r0 = w * 16 + (lane >> 2);
    const int r1 = 64 + w * 16 + (lane >> 2);
    const int c16 = lane & 3;
    const bf16* aP0 = hbuf + (size_t)(row0 + r0) * F_DIM + c16 * 8;
    const bf16* aP1 = hbuf + (size_t)(row0 + r1) * F_DIM + c16 * 8;
    const bf16* bP0 = W2t + ((size_t)e * D_DIM + d0 + r0) * F_DIM + c16 * 8;
    const bf16* bP1 = W2t + ((size_t)e * D_DIM + d0 + r1) * F_DIM + c16 * 8;

    const unsigned dO0 = __builtin_amdgcn_readfirstlane(w * 1024);
    const unsigned dO1 = __builtin_amdgcn_readfirstlane(4096 + w * 1024);

    const int wrow = (w >> 1) * 64, wcol = (w & 1) * 64;
    const int fr = lane & 15, fk = (lane >> 4) * 8;

    float4v acc[4][4];
#pragma unroll
    for (int m = 0; m < 4; ++m)
#pragma unroll
        for (int n = 0; n < 4; ++n)
#pragma unroll
            for (int r = 0; r < 4; ++r) acc[m][n][r] = 0.f;

    auto stage = [&](int kt, bf16* A, bf16* B) {
        const int ko = kt * 32;
        gl_lds16(aP0 + ko, (bf16*)((char*)A + dO0));
        gl_lds16(aP1 + ko, (bf16*)((char*)A + dO1));
        gl_lds16(bP0 + ko, (bf16*)((char*)B + dO0));
        gl_lds16(bP1 + ko, (bf16*)((char*)B + dO1));
    };
    auto comp = [&](const bf16* A, const bf16* B) {
        bf16x8 af[4], bfr[4];
#pragma unroll
        for (int m = 0; m < 4; ++m)
            af[m] = *(const bf16x8*)&A[(wrow + m * 16 + fr) * 32 + fk];
#pragma unroll
        for (int n = 0; n < 4; ++n)
            bfr[n] = *(const bf16x8*)&B[(wcol + n * 16 + fr) * 32 + fk];
#pragma unroll
        for (int m = 0; m < 4; ++m)
#pragma unroll
            for (int n = 0; n < 4; ++n)
                acc[m][n] = __builtin_amdgcn_mfma_f32_16x16x32_bf16(af[m], bfr[n],
                                                                   acc[m][n], 0, 0, 0);
    };

    const int NKT = F_DIM / 32;  // 128, even
    stage(0, As0, Bs0);
    __syncthreads();
    for (int kt = 0; kt < NKT; kt += 2) {
        if (kt + 1 < NKT) stage(kt + 1, As1, Bs1);
        comp(As0, Bs0);
        __syncthreads();
        if (kt + 2 < NKT) stage(kt + 2, As0, Bs0);
        comp(As1, Bs1);
        __syncthreads();
    }

#pragma unroll
    for (int n = 0; n < 4; ++n) {
        const int gcol = d0 + wcol + n * 16 + fr;
        const float bias = b2[e * D_DIM + gcol];
#pragma unroll
        for (int m = 0; m < 4; ++m) {
#pragma unroll
            for (int r = 0; r < 4; ++r) {
                const int lrow = wrow + m * 16 + (lane >> 4) * 4 + r;
                const int t = toks[lrow];
                if (t >= 0) {
                    const float v = (acc[m][n][r] + bias) * gates_s[lrow];
                    atomicAdd(&out[(size_t)t * D_DIM + gcol], v);
                }
            }
        }
    }
}

extern "C" void kernel_launch(void* const* d_in, const int* in_sizes, int n_in,
                              void* d_out, int out_size, void* d_ws, size_t ws_size,
                              hipStream_t stream) {
    const float* x = (const float*)d_in[0];
    const float* Wg = (const float*)d_in[1];
    const float* bg = (const float*)d_in[2];
    const float* W1 = (const float*)d_in[3];
    const float* b1 = (const float*)d_in[4];
    const float* W2 = (const float*)d_in[5];
    const float* b2 = (const float*)d_in[6];
    float* out = (float*)d_out;

    char* ws = (char*)d_ws;
    int* counts = (int*)(ws + 0);       // 8 ints
    int* cursors = (int*)(ws + 32);     // 8 ints
    int* offsets = (int*)(ws + 64);     // 9 ints
    int* top_idx = (int*)(ws + 256);                     // T*2 ints
    float* top_gate = (float*)(ws + 256 + 65536);        // T*2 floats
    int* tok_list = (int*)(ws + 256 + 2 * 65536);        // MAX_ROWS ints
    float* gate_list = (float*)(ws + 256 + 2 * 65536 + 69632);
    size_t off = 256 + 2 * 65536 + 2 * 69632;            // 270592, 256-aligned
    bf16* xb = (bf16*)(ws + off);
    off += (size_t)T_TOK * D_DIM * 2;
    bf16* W1t = (bf16*)(ws + off);
    off += (size_t)E_NUM * D_DIM * F_DIM * 2;
    bf16* W2t = (bf16*)(ws + off);
    off += (size_t)E_NUM * D_DIM * F_DIM * 2;
    bf16* hbuf = (bf16*)(ws + off);

    hipMemsetAsync(d_out, 0, (size_t)T_TOK * D_DIM * sizeof(float), stream);
    hipMemsetAsync(ws, 0, 64, stream);                       // counts + cursors
    hipMemsetAsync(tok_list, 0xFF, (size_t)MAX_ROWS * 4, stream);  // -1 sentinels

    xcvt_kernel<<<T_TOK * D_DIM / 4 / 256, 256, 0, stream>>>(x, xb);
    transpose_cvt<<<dim3(F_DIM / 64, D_DIM / 64, E_NUM), dim3(256), 0, stream>>>(
        W1, W1t, D_DIM, F_DIM);
    transpose_cvt<<<dim3(D_DIM / 64, F_DIM / 64, E_NUM), dim3(256), 0, stream>>>(
        W2, W2t, F_DIM, D_DIM);
    router_kernel<<<T_TOK / 4, 256, 0, stream>>>(x, Wg, bg, top_idx, top_gate, counts);
    offsets_kernel<<<1, 64, 0, stream>>>(counts, offsets);
    scatter_kernel<<<T_TOK / 256, 256, 0, stream>>>(top_idx, top_gate, offsets, cursors,
                                                    tok_list, gate_list);
    gemm1_kernel<<<NUM_RB * (F_DIM / 128), 256, 0, stream>>>(xb, W1t, b1, tok_list,
                                                             offsets, hbuf);
    gemm2_kernel<<<NUM_RB * (D_DIM / 128), 256, 0, stream>>>(hbuf, W2t, b2, tok_list,
                                                             gate_list, offsets, out);
}

// Round 4
// 850.604 us; speedup vs baseline: 1.1768x; 1.0177x over previous
//
#include <hip/hip_runtime.h>
#include <hip/hip_bf16.h>

#define T_TOK 8192
#define D_DIM 1024
#define F_DIM 4096
#define E_NUM 8
#define BM 128
#define MAX_ROWS (2 * T_TOK + E_NUM * BM)   // 17408
#define NUM_RB (MAX_ROWS / BM)              // 136

typedef __hip_bfloat16 bf16;
using bf16x8  = __attribute__((ext_vector_type(8))) __bf16;
using float4v = __attribute__((ext_vector_type(4))) float;

// async global->LDS, 16B per lane; dest = uniform base + lane*16
__device__ inline void gl_lds16(const bf16* g, bf16* l) {
    __builtin_amdgcn_global_load_lds(
        (const __attribute__((address_space(1))) void*)g,
        (__attribute__((address_space(3))) void*)l, 16, 0, 0);
}

// One pipeline phase: consume LDS tile (CA,CB), prefetch K-step KST into the
// same buffers. Counted vmcnt keeps the other buffer's 4 loads in flight.
#define PH(WAITSTR, CA, CB, DOSTAGE, KST)                                      \
    do {                                                                       \
        asm volatile("s_waitcnt " WAITSTR ::: "memory");                       \
        __builtin_amdgcn_s_barrier();                                          \
        bf16x8 af[4], bfr[4];                                                  \
        _Pragma("unroll")                                                      \
        for (int m_ = 0; m_ < 4; ++m_)                                         \
            af[m_] = *(const bf16x8*)&(CA)[(wrow + m_ * 16 + fr) * 32 + fkk];  \
        _Pragma("unroll")                                                      \
        for (int n_ = 0; n_ < 4; ++n_)                                         \
            bfr[n_] = *(const bf16x8*)&(CB)[(wcol + n_ * 16 + fr) * 32 + fkk]; \
        asm volatile("s_waitcnt lgkmcnt(0)" ::: "memory");                     \
        __builtin_amdgcn_sched_barrier(0);                                     \
        __builtin_amdgcn_s_barrier();                                          \
        if (DOSTAGE) stage(KST, CA, CB);                                       \
        __builtin_amdgcn_s_setprio(1);                                         \
        _Pragma("unroll")                                                      \
        for (int m_ = 0; m_ < 4; ++m_)                                         \
            _Pragma("unroll")                                                  \
            for (int n_ = 0; n_ < 4; ++n_)                                     \
                acc[m_][n_] = __builtin_amdgcn_mfma_f32_16x16x32_bf16(         \
                    af[m_], bfr[n_], acc[m_][n_], 0, 0, 0);                    \
        __builtin_amdgcn_s_setprio(0);                                         \
    } while (0)

// ---------------- x -> bf16 ----------------
__global__ __launch_bounds__(256) void xcvt_kernel(const float* __restrict__ x,
                                                   bf16* __restrict__ xb) {
    const int i = blockIdx.x * 256 + threadIdx.x;  // over T*D/4
    float4 v = ((const float4*)x)[i];
    bf16 tmp[4];
    tmp[0] = __float2bfloat16(v.x);
    tmp[1] = __float2bfloat16(v.y);
    tmp[2] = __float2bfloat16(v.z);
    tmp[3] = __float2bfloat16(v.w);
    ((ushort4*)xb)[i] = *(const ushort4*)tmp;
}

// ------- transpose+convert: src[e][M][N] f32 -> dst[e][N][M] bf16, 64x64 tiles -------
__global__ __launch_bounds__(256) void transpose_cvt(const float* __restrict__ src,
                                                     bf16* __restrict__ dst,
                                                     int M, int N) {
    __shared__ float tile[64][65];
    const int e = blockIdx.z;
    const float* s = src + (size_t)e * M * N;
    bf16* d = dst + (size_t)e * M * N;
    const int n0 = blockIdx.x * 64, m0 = blockIdx.y * 64;
    const int tx = threadIdx.x & 15, ty = threadIdx.x >> 4;
#pragma unroll
    for (int i = 0; i < 4; ++i) {
        const int r = ty + i * 16;
        const float4 v = *(const float4*)&s[(size_t)(m0 + r) * N + n0 + tx * 4];
        tile[r][tx * 4 + 0] = v.x;
        tile[r][tx * 4 + 1] = v.y;
        tile[r][tx * 4 + 2] = v.z;
        tile[r][tx * 4 + 3] = v.w;
    }
    __syncthreads();
#pragma unroll
    for (int i = 0; i < 4; ++i) {
        const int nc = ty + i * 16;
        bf16 o[4];
#pragma unroll
        for (int j = 0; j < 4; ++j) o[j] = __float2bfloat16(tile[tx * 4 + j][nc]);
        *(ushort4*)&d[(size_t)(n0 + nc) * M + m0 + tx * 4] = *(const ushort4*)o;
    }
}

// ---------------- router: logits (fp32), top-2, softmax, counts ----------------
__global__ __launch_bounds__(256) void router_kernel(
    const float* __restrict__ x, const float* __restrict__ Wg,
    const float* __restrict__ bg, int* __restrict__ top_idx,
    float* __restrict__ top_gate, int* __restrict__ counts) {
    __shared__ float wg_s[E_NUM][D_DIM];
    for (int i = threadIdx.x; i < D_DIM * E_NUM; i += 256)
        wg_s[i & 7][i >> 3] = Wg[i];
    __syncthreads();

    const int lane = threadIdx.x & 63;
    const int t = blockIdx.x * 4 + (threadIdx.x >> 6);
    float acc[E_NUM];
#pragma unroll
    for (int e = 0; e < E_NUM; ++e) acc[e] = 0.f;
    const float* xrow = x + (size_t)t * D_DIM;
    for (int d = lane; d < D_DIM; d += 64) {
        const float xv = xrow[d];
#pragma unroll
        for (int e = 0; e < E_NUM; ++e) acc[e] += xv * wg_s[e][d];
    }
#pragma unroll
    for (int off = 32; off > 0; off >>= 1) {
#pragma unroll
        for (int e = 0; e < E_NUM; ++e) acc[e] += __shfl_xor(acc[e], off, 64);
    }
    if (lane == 0) {
        float v[E_NUM];
#pragma unroll
        for (int e = 0; e < E_NUM; ++e) v[e] = acc[e] + bg[e];
        int i0 = 0;
#pragma unroll
        for (int e = 1; e < E_NUM; ++e)
            if (v[e] > v[i0]) i0 = e;
        int i1 = -1;
#pragma unroll
        for (int e = 0; e < E_NUM; ++e) {
            if (e == i0) continue;
            if (i1 < 0 || v[e] > v[i1]) i1 = e;
        }
        const float g0 = 1.f / (1.f + expf(v[i1] - v[i0]));
        top_idx[2 * t] = i0;
        top_idx[2 * t + 1] = i1;
        top_gate[2 * t] = g0;
        top_gate[2 * t + 1] = 1.f - g0;
        atomicAdd(&counts[i0], 1);
        atomicAdd(&counts[i1], 1);
    }
}

// ---------------- padded segment offsets ----------------
__global__ void offsets_kernel(const int* __restrict__ counts, int* __restrict__ offsets) {
    if (threadIdx.x == 0) {
        int off = 0;
#pragma unroll
        for (int e = 0; e < E_NUM; ++e) {
            offsets[e] = off;
            off += (counts[e] + BM - 1) / BM * BM;
        }
        offsets[E_NUM] = off;
    }
}

// ---------------- scatter tokens into expert segments ----------------
__global__ __launch_bounds__(256) void scatter_kernel(
    const int* __restrict__ top_idx, const float* __restrict__ top_gate,
    const int* __restrict__ offsets, int* __restrict__ cursors,
    int* __restrict__ tok_list, float* __restrict__ gate_list) {
    const int t = blockIdx.x * 256 + threadIdx.x;
    if (t >= T_TOK) return;
#pragma unroll
    for (int j = 0; j < 2; ++j) {
        const int e = top_idx[2 * t + j];
        const int pos = atomicAdd(&cursors[e], 1);
        const int slot = offsets[e] + pos;
        tok_list[slot] = t;
        gate_list[slot] = top_gate[2 * t + j];
    }
}

// ---------------- GEMM1: h = relu(gather(x) @ W1[e] + b1[e]) -> bf16 ----------
// Counted-vmcnt 2-buffer pipeline + T2 both-sides LDS swizzle + T5 setprio.
__global__ __launch_bounds__(256, 4) void gemm1_kernel(
    const bf16* __restrict__ xb, const bf16* __restrict__ W1t,
    const float* __restrict__ b1, const int* __restrict__ tok_list,
    const int* __restrict__ offsets, bf16* __restrict__ hbuf) {
    __shared__ bf16 As0[BM * 32];
    __shared__ bf16 As1[BM * 32];
    __shared__ bf16 Bs0[BM * 32];
    __shared__ bf16 Bs1[BM * 32];
    __shared__ int toks[BM];

    const int NCB = F_DIM / 128;          // 32
    const int per = (NUM_RB * NCB) / 8;   // 544
    const int flat = blockIdx.x;
    const int sw = (flat & 7) * per + (flat >> 3);
    const int rb = sw / NCB, cb = sw % NCB;

    const int row0 = rb * BM;
    const int total = offsets[E_NUM];
    if (row0 >= total) return;
    int e = 0;
#pragma unroll
    for (int i = 1; i < E_NUM; ++i) e += (row0 >= offsets[i]) ? 1 : 0;

    const int tid = threadIdx.x;
    if (tid < BM) toks[tid] = tok_list[row0 + tid];
    __syncthreads();   // full drain: only our stage loads count toward vmcnt after this

    const int lane = tid & 63;
    const int w = tid >> 6;
    const int f0 = cb * 128;

    // staging geometry: dest row = w*16 + lane/4 (+64), dest chunk = lane&3.
    // T2 pre-swizzled SOURCE chunk: c ^ ((row>>1)&3) = (lane&3) ^ ((lane>>3)&3)
    const int r0 = w * 16 + (lane >> 2);
    const int r1 = 64 + w * 16 + (lane >> 2);
    const int c16 = (lane & 3) ^ ((lane >> 3) & 3);
    int t0 = toks[r0]; if (t0 < 0) t0 = 0;
    int t1 = toks[r1]; if (t1 < 0) t1 = 0;
    const bf16* aP0 = xb + (size_t)t0 * D_DIM + c16 * 8;
    const bf16* aP1 = xb + (size_t)t1 * D_DIM + c16 * 8;
    const bf16* bP0 = W1t + ((size_t)e * F_DIM + f0 + r0) * D_DIM + c16 * 8;
    const bf16* bP1 = W1t + ((size_t)e * F_DIM + f0 + r1) * D_DIM + c16 * 8;

    const unsigned dO0 = __builtin_amdgcn_readfirstlane(w * 1024);
    const unsigned dO1 = __builtin_amdgcn_readfirstlane(4096 + w * 1024);

    const int wrow = (w >> 1) * 64, wcol = (w & 1) * 64;
    const int fr = lane & 15;
    // swizzled read chunk: (lane>>4) ^ ((row>>1)&3), row bits 1-2 == lane bits 1-2
    const int fkk = 8 * ((lane >> 4) ^ ((lane >> 1) & 3));

    float4v acc[4][4];
#pragma unroll
    for (int m = 0; m < 4; ++m)
#pragma unroll
        for (int n = 0; n < 4; ++n)
#pragma unroll
            for (int r = 0; r < 4; ++r) acc[m][n][r] = 0.f;

    auto stage = [&](int kt, bf16* A, bf16* B) {
        const int ko = kt * 32;
        gl_lds16(aP0 + ko, (bf16*)((char*)A + dO0));
        gl_lds16(aP1 + ko, (bf16*)((char*)A + dO1));
        gl_lds16(bP0 + ko, (bf16*)((char*)B + dO0));
        gl_lds16(bP1 + ko, (bf16*)((char*)B + dO1));
    };

    const int NKT = D_DIM / 32;  // 32
    stage(0, As0, Bs0);
    stage(1, As1, Bs1);
    for (int kt = 0; kt < NKT - 2; kt += 2) {
        PH("vmcnt(4)", As0, Bs0, true, kt + 2);
        PH("vmcnt(4)", As1, Bs1, true, kt + 3);
    }
    PH("vmcnt(4)", As0, Bs0, false, 0);
    PH("vmcnt(0)", As1, Bs1, false, 0);

#pragma unroll
    for (int n = 0; n < 4; ++n) {
        const int gcol = f0 + wcol + n * 16 + fr;
        const float bias = b1[e * F_DIM + gcol];
#pragma unroll
        for (int m = 0; m < 4; ++m) {
#pragma unroll
            for (int r = 0; r < 4; ++r) {
                const int grow = row0 + wrow + m * 16 + (lane >> 4) * 4 + r;
                float v = acc[m][n][r] + bias;
                v = fmaxf(v, 0.f);
                hbuf[(size_t)grow * F_DIM + gcol] = __float2bfloat16(v);
            }
        }
    }
}

// ---------------- GEMM2: out[tok] += gate * (h @ W2[e] + b2[e]) ----------------
__global__ __launch_bounds__(256, 4) void gemm2_kernel(
    const bf16* __restrict__ hbuf, const bf16* __restrict__ W2t,
    const float* __restrict__ b2, const int* __restrict__ tok_list,
    const float* __restrict__ gate_list, const int* __restrict__ offsets,
    float* __restrict__ out) {
    __shared__ bf16 As0[BM * 32];
    __shared__ bf16 As1[BM * 32];
    __shared__ bf16 Bs0[BM * 32];
    __shared__ bf16 Bs1[BM * 32];
    __shared__ int toks[BM];
    __shared__ float gates_s[BM];

    const int NCB = D_DIM / 128;          // 8
    const int per = (NUM_RB * NCB) / 8;   // 136
    const int flat = blockIdx.x;
    const int sw = (flat & 7) * per + (flat >> 3);
    const int rb = sw / NCB, cb = sw % NCB;

    const int row0 = rb * BM;
    const int total = offsets[E_NUM];
    if (row0 >= total) return;
    int e = 0;
#pragma unroll
    for (int i = 1; i < E_NUM; ++i) e += (row0 >= offsets[i]) ? 1 : 0;

    const int tid = threadIdx.x;
    if (tid < BM) {
        int t = tok_list[row0 + tid];
        toks[tid] = t;
        gates_s[tid] = (t >= 0) ? gate_list[row0 + tid] : 0.f;
    }
    __syncthreads();

    const int lane = tid & 63;
    const int w = tid >> 6;
    const int d0 = cb * 128;

    const int r0 = w * 16 + (lane >> 2);
    const int r1 = 64 + w * 16 + (lane >> 2);
    const int c16 = (lane & 3) ^ ((lane >> 3) & 3);
    const bf16* aP0 = hbuf + (size_t)(row0 + r0) * F_DIM + c16 * 8;
    const bf16* aP1 = hbuf + (size_t)(row0 + r1) * F_DIM + c16 * 8;
    const bf16* bP0 = W2t + ((size_t)e * D_DIM + d0 + r0) * F_DIM + c16 * 8;
    const bf16* bP1 = W2t + ((size_t)e * D_DIM + d0 + r1) * F_DIM + c16 * 8;

    const unsigned dO0 = __builtin_amdgcn_readfirstlane(w * 1024);
    const unsigned dO1 = __builtin_amdgcn_readfirstlane(4096 + w * 1024);

    const int wrow = (w >> 1) * 64, wcol = (w & 1) * 64;
    const int fr = lane & 15;
    const int fkk = 8 * ((lane >> 4) ^ ((lane >> 1) & 3));

    float4v acc[4][4];
#pragma unroll
    for (int m = 0; m < 4; ++m)
#pragma unroll
        for (int n = 0; n < 4; ++n)
#pragma unroll
            for (int r = 0; r < 4; ++r) acc[m][n][r] = 0.f;

    auto stage = [&](int kt, bf16* A, bf16* B) {
        const int ko = kt * 32;
        gl_lds16(aP0 + ko, (bf16*)((char*)A + dO0));
        gl_lds16(aP1 + ko, (bf16*)((char*)A + dO1));
        gl_lds16(bP0 + ko, (bf16*)((char*)B + dO0));
        gl_lds16(bP1 + ko, (bf16*)((char*)B + dO1));
    };

    const int NKT = F_DIM / 32;  // 128
    stage(0, As0, Bs0);
    stage(1, As1, Bs1);
    for (int kt = 0; kt < NKT - 2; kt += 2) {
        PH("vmcnt(4)", As0, Bs0, true, kt + 2);
        PH("vmcnt(4)", As1, Bs1, true, kt + 3);
    }
    PH("vmcnt(4)", As0, Bs0, false, 0);
    PH("vmcnt(0)", As1, Bs1, false, 0);

#pragma unroll
    for (int n = 0; n < 4; ++n) {
        const int gcol = d0 + wcol + n * 16 + fr;
        const float bias = b2[e * D_DIM + gcol];
#pragma unroll
        for (int m = 0; m < 4; ++m) {
#pragma unroll
            for (int r = 0; r < 4; ++r) {
                const int lrow = wrow + m * 16 + (lane >> 4) * 4 + r;
                const int t = toks[lrow];
                if (t >= 0) {
                    const float v = (acc[m][n][r] + bias) * gates_s[lrow];
                    atomicAdd(&out[(size_t)t * D_DIM + gcol], v);
                }
            }
        }
    }
}

extern "C" void kernel_launch(void* const* d_in, const int* in_sizes, int n_in,
                              void* d_out, int out_size, void* d_ws, size_t ws_size,
                              hipStream_t stream) {
    const float* x = (const float*)d_in[0];
    const float* Wg = (const float*)d_in[1];
    const float* bg = (const float*)d_in[2];
    const float* W1 = (const float*)d_in[3];
    const float* b1 = (const float*)d_in[4];
    const float* W2 = (const float*)d_in[5];
    const float* b2 = (const float*)d_in[6];
    float* out = (float*)d_out;

    char* ws = (char*)d_ws;
    int* counts = (int*)(ws + 0);       // 8 ints
    int* cursors = (int*)(ws + 32);     // 8 ints
    int* offsets = (int*)(ws + 64);     // 9 ints
    int* top_idx = (int*)(ws + 256);                     // T*2 ints
    float* top_gate = (float*)(ws + 256 + 65536);        // T*2 floats
    int* tok_list = (int*)(ws + 256 + 2 * 65536);        // MAX_ROWS ints
    float* gate_list = (float*)(ws + 256 + 2 * 65536 + 69632);
    size_t off = 256 + 2 * 65536 + 2 * 69632;            // 270592, 256-aligned
    bf16* xb = (bf16*)(ws + off);
    off += (size_t)T_TOK * D_DIM * 2;
    bf16* W1t = (bf16*)(ws + off);
    off += (size_t)E_NUM * D_DIM * F_DIM * 2;
    bf16* W2t = (bf16*)(ws + off);
    off += (size_t)E_NUM * D_DIM * F_DIM * 2;
    bf16* hbuf = (bf16*)(ws + off);

    hipMemsetAsync(d_out, 0, (size_t)T_TOK * D_DIM * sizeof(float), stream);
    hipMemsetAsync(ws, 0, 64, stream);                       // counts + cursors
    hipMemsetAsync(tok_list, 0xFF, (size_t)MAX_ROWS * 4, stream);  // -1 sentinels

    xcvt_kernel<<<T_TOK * D_DIM / 4 / 256, 256, 0, stream>>>(x, xb);
    transpose_cvt<<<dim3(F_DIM / 64, D_DIM / 64, E_NUM), dim3(256), 0, stream>>>(
        W1, W1t, D_DIM, F_DIM);
    transpose_cvt<<<dim3(D_DIM / 64, F_DIM / 64, E_NUM), dim3(256), 0, stream>>>(
        W2, W2t, F_DIM, D_DIM);
    router_kernel<<<T_TOK / 4, 256, 0, stream>>>(x, Wg, bg, top_idx, top_gate, counts);
    offsets_kernel<<<1, 64, 0, stream>>>(counts, offsets);
    scatter_kernel<<<T_TOK / 256, 256, 0, stream>>>(top_idx, top_gate, offsets, cursors,
                                                    tok_list, gate_list);
    gemm1_kernel<<<NUM_RB * (F_DIM / 128), 256, 0, stream>>>(xb, W1t, b1, tok_list,
                                                             offsets, hbuf);
    gemm2_kernel<<<NUM_RB * (D_DIM / 128), 256, 0, stream>>>(hbuf, W2t, b2, tok_list,
                                                             gate_list, offsets, out);
}